// Round 13
// baseline (428.297 us; speedup 1.0000x reference)
//
#include <hip/hip_runtime.h>
#include <hip/hip_bf16.h>
#include <hip/hip_fp8.h>

#define N_NODES 200000
#define N_EDGES 4000000
#define R_REL   4
#define D_DIM   64
#define G_GRAPHS 64
#define C_CLS   10
#define NR      (N_NODES * R_REL)      // 800000
#define POOL_BLOCKS 128

// 2-pass radix CSR build
#define NCB   391                       // ceil(NR / 2048) coarse buckets (key>>11)
#define LCAP  64                        // LDS bin cap (lambda=20.9, +9.3 sigma)
#define CCAP  11264                     // coarse bucket cap (lambda=10230, +10 sigma)
#define EPB   8192                      // edges per k_coarse block (512 thr x 16)

#define EMBED_BLOCKS 12500              // N*16/256
#define BOUNDS_BLOCKS 782               // ceil(N/256)

#define MS    72                        // m_lds row stride in shorts (144 B)
#define H8SCALE 64.0f                   // fp8 shadow scale
#define H8INV   (1.0f / 64.0f)

typedef __attribute__((ext_vector_type(8))) short short8v;   // 8 bf16 (4 VGPR)
typedef __attribute__((ext_vector_type(4))) float f32x4;

__device__ __forceinline__ unsigned short to_bf16(float x) {
    __hip_bfloat16 b = __float2bfloat16(x);
    return *(unsigned short*)&b;
}
__device__ __forceinline__ unsigned char to_fp8(float x) {
    __hip_fp8_e4m3 v(x);
    return *(unsigned char*)&v;
}
__device__ __forceinline__ float from_fp8(unsigned int b) {
    __hip_fp8_e4m3 v;
    v.__x = (__hip_fp8_storage_t)b;
    return (float)v;
}

// accumulate 8 fp8 channels from a uint2
#define ACC8F8(u) \
    a0 += from_fp8((u).x & 255);         \
    a1 += from_fp8(((u).x >> 8) & 255);  \
    a2 += from_fp8(((u).x >> 16) & 255); \
    a3 += from_fp8((u).x >> 24);         \
    a4 += from_fp8((u).y & 255);         \
    a5 += from_fp8(((u).y >> 8) & 255);  \
    a6 += from_fp8(((u).y >> 16) & 255); \
    a7 += from_fp8((u).y >> 24);

// ---------------- CSR build pass 1: LDS-staged coarse binning ----------------
// entry = (key & 2047) << 18 | src   (11 + 18 bits)

__global__ __launch_bounds__(512) void k_coarse(
    const int* __restrict__ src, const int* __restrict__ tgt,
    const int* __restrict__ et,
    int* __restrict__ gcur, unsigned int* __restrict__ coarse) {
    __shared__ unsigned int bins[NCB * LCAP];   // 100 KB
    __shared__ int lcnt[NCB], lpos[NCB];

    const int tid = threadIdx.x;
    for (int i = tid; i < NCB; i += 512) lcnt[i] = 0;
    __syncthreads();

#pragma unroll
    for (int h = 0; h < 4; ++h) {
        int e4 = blockIdx.x * EPB + (h * 512 + tid) * 4;
        if (e4 < N_EDGES) {
            int4 s = *(const int4*)&src[e4];
            int4 t = *(const int4*)&tgt[e4];
            int4 r = *(const int4*)&et[e4];
#define PUT(ss, tt, rr) { \
                int key = (tt) * R_REL + (rr); \
                int b = key >> 11; \
                int p = atomicAdd(&lcnt[b], 1); \
                if (p < LCAP) bins[b * LCAP + p] = \
                    ((unsigned int)(key & 2047) << 18) | (unsigned int)(ss); \
            }
            PUT(s.x, t.x, r.x); PUT(s.y, t.y, r.y);
            PUT(s.z, t.z, r.z); PUT(s.w, t.w, r.w);
#undef PUT
        }
    }
    __syncthreads();

    for (int i = tid; i < NCB; i += 512) {
        int c = lcnt[i]; if (c > LCAP) c = LCAP;
        lcnt[i] = c;
        lpos[i] = atomicAdd(&gcur[i], c);
    }
    __syncthreads();

    for (int j = tid; j < NCB * LCAP; j += 512) {
        int b = j >> 6, l = j & 63;
        if (l < lcnt[b]) {
            int gp = lpos[b] + l;
            if (gp < CCAP) coarse[(size_t)b * CCAP + gp] = bins[j];
        }
    }
}

// ---------------- CSR build pass 2: per-bucket fine counting sort ----------------

__global__ __launch_bounds__(1024) void k_fine(
    const int* __restrict__ gcur, const unsigned int* __restrict__ coarse,
    int* __restrict__ off, int* __restrict__ srcSorted) {
    __shared__ unsigned int ent[CCAP];   // 45 KB
    __shared__ int hist[2048];           // 8 KB
    __shared__ int pre[512];             // 2 KB

    const int cb = blockIdx.x, tid = threadIdx.x;

    int v = 0;
    if (tid < 512) {
        v = (tid < NCB) ? gcur[tid] : 0;
        if (v > CCAP) v = CCAP;
        pre[tid] = v;
    }
    __syncthreads();
    for (int d = 1; d < 512; d <<= 1) {
        int t = 0;
        if (tid < 512 && tid >= d) t = pre[tid - d];
        __syncthreads();
        if (tid < 512) pre[tid] += t;
        __syncthreads();
    }
    const int gb = (cb > 0) ? pre[cb - 1] : 0;

    int cnt = gcur[cb]; if (cnt > CCAP) cnt = CCAP;
    const int key0 = cb << 11;
    const unsigned int* cp = coarse + (size_t)cb * CCAP;

    for (int i = tid; i < cnt; i += 1024) ent[i] = cp[i];
    hist[tid] = 0; hist[tid + 1024] = 0;
    __syncthreads();

    for (int i = tid; i < cnt; i += 1024) atomicAdd(&hist[ent[i] >> 18], 1);
    __syncthreads();

    int x0 = hist[tid], x1 = hist[tid + 1024];
    for (int d = 1; d < 2048; d <<= 1) {
        int v0 = (tid >= d) ? hist[tid - d] : 0;
        int v1 = hist[tid + 1024 - d];
        __syncthreads();
        hist[tid] += v0;
        hist[tid + 1024] += v1;
        __syncthreads();
    }
    int excl0 = hist[tid] - x0;
    int excl1 = hist[tid + 1024] - x1;
    __syncthreads();
    hist[tid] = excl0;                   // becomes scatter cursor
    hist[tid + 1024] = excl1;

    int key = key0 + tid;
    if (key < NR) off[key] = gb + excl0;
    key = key0 + tid + 1024;
    if (key < NR) off[key] = gb + excl1;
    if (cb == NCB - 1 && tid == 0) off[NR] = N_EDGES;
    __syncthreads();

    for (int i = tid; i < cnt; i += 1024) {
        unsigned int e = ent[i];
        int pos = atomicAdd(&hist[e >> 18], 1);
        srcSorted[gb + pos] = (int)(e & 0x3FFFFu);
    }
}

// ---------------- fused misc: embed (bf16 + fp8 shadow) + bounds + weight prep ----------------

struct WPtrs { const float* p[15]; };

__global__ void k_misc(const int* __restrict__ xop, const int* __restrict__ xcat,
                       const float4* __restrict__ opemb, const float4* __restrict__ catemb,
                       ushort4* __restrict__ hb, uchar4* __restrict__ hb8,
                       const int* __restrict__ batch, int* __restrict__ start,
                       WPtrs wp, unsigned short* __restrict__ wfrag) {
    int bid = blockIdx.x;
    if (bid < EMBED_BLOCKS) {
        int i = bid * 256 + threadIdx.x;
        if (i < N_NODES * 16) {
            int n = i >> 4, q = i & 15;
            float4 a = opemb[xop[n] * 16 + q];
            float4 b = catemb[xcat[n] * 16 + q];
            float4 r = make_float4(a.x + b.x, a.y + b.y, a.z + b.z, a.w + b.w);
            ushort4 ub;
            ub.x = to_bf16(r.x); ub.y = to_bf16(r.y);
            ub.z = to_bf16(r.z); ub.w = to_bf16(r.w);
            hb[i] = ub;
            uchar4 u8;
            u8.x = to_fp8(r.x * H8SCALE); u8.y = to_fp8(r.y * H8SCALE);
            u8.z = to_fp8(r.z * H8SCALE); u8.w = to_fp8(r.w * H8SCALE);
            hb8[i] = u8;
        }
    } else if (bid < EMBED_BLOCKS + BOUNDS_BLOCKS) {
        int i = (bid - EMBED_BLOCKS) * 256 + threadIdx.x;
        if (i >= N_NODES) return;
        int b = batch[i];
        if (i == 0) {
            for (int g = 0; g <= b; ++g) start[g] = 0;
        } else {
            int p = batch[i - 1];
            for (int g = p + 1; g <= b; ++g) start[g] = i;
        }
        if (i == N_NODES - 1) {
            for (int g = b + 1; g <= G_GRAPHS; ++g) start[g] = N_NODES;
        }
    } else {
        int m = bid - EMBED_BLOCKS - BOUNDS_BLOCKS;    // 0..14
        const float* W = wp.p[m];
        unsigned short* outp = wfrag + m * 4096;
        for (int f = threadIdx.x; f < 4096; f += 256) {
            int j = f & 7, lane = (f >> 3) & 63, c0t = (f >> 9) & 3, kk = f >> 11;
            int k  = kk * 32 + (lane >> 4) * 8 + j;
            int ch = c0t * 16 + (lane & 15);
            outp[f] = to_bf16(W[k * 64 + ch]);
        }
    }
}

// ---------------- fused RGCN layer: fp8 gather-aggregate (LDS m tile) + MFMA ----------------
// Block = 512 threads (8 waves), 64 nodes = 256 keys; LDS = m_lds only (36.9 KB)
// -> 4 blocks/CU, cross-block phase A/B overlap. B-frags read from global (L2-hot).
// Phase A: wave w aggregates keys [w*32, w*32+32) in four 8-key register passes;
//   gathers from the fp8 shadow (64 B/row, half the line traffic); scale folded
//   into the mean divisor; means stored bf16 in m_lds [256][MS].
// Phase B: wave (ct=wid&3) does node tiles nt=(wid>>2) and (wid>>2)+2.

template <int RELU>
__global__ __launch_bounds__(512) void k_layer(
    const unsigned short* __restrict__ hb_in,   // [N][64] bf16 (root pass)
    const unsigned char*  __restrict__ hb8_in,  // [N][64] fp8 (gathers, x64 scale)
    unsigned short* __restrict__ hb_out,        // [N][64] bf16
    unsigned char*  __restrict__ hb8_out,       // [N][64] fp8
    const int* __restrict__ off, const int* __restrict__ srcSorted,
    const unsigned short* __restrict__ wfrag,   // this layer: [5][2][4][64][8] bf16
    const float* __restrict__ bias)             // [64]
{
    __shared__ unsigned short m_lds[256 * MS];  // 36864 B

    const int tid  = threadIdx.x;
    const int lane = tid & 63, wid = tid >> 6;  // 8 waves
    const int g = lane >> 3, q = lane & 7;
    const int nbase = blockIdx.x * 64;

    // ---- phase A: aggregate 32 keys per wave into m_lds ----
    const unsigned char* base8 = hb8_in + q * 8;
#pragma unroll
    for (int p = 0; p < 4; ++p) {
        const int keyLocal = wid * 32 + p * 8 + g;
        const int key = nbase * R_REL + keyLocal;
        const int e0 = off[key];
        const int e1 = off[key + 1];

        float a0 = 0.f, a1 = 0.f, a2 = 0.f, a3 = 0.f,
              a4 = 0.f, a5 = 0.f, a6 = 0.f, a7 = 0.f;

        int e = e0;
        for (; e + 4 <= e1; e += 4) {
            int s0 = srcSorted[e];
            int s1 = srcSorted[e + 1];
            int s2 = srcSorted[e + 2];
            int s3 = srcSorted[e + 3];
            uint2 u0 = *(const uint2*)(base8 + (size_t)s0 * D_DIM);
            uint2 u1 = *(const uint2*)(base8 + (size_t)s1 * D_DIM);
            uint2 u2 = *(const uint2*)(base8 + (size_t)s2 * D_DIM);
            uint2 u3 = *(const uint2*)(base8 + (size_t)s3 * D_DIM);
            ACC8F8(u0); ACC8F8(u1); ACC8F8(u2); ACC8F8(u3);
        }
        for (; e < e1; ++e) {
            int s0 = srcSorted[e];
            uint2 u0 = *(const uint2*)(base8 + (size_t)s0 * D_DIM);
            ACC8F8(u0);
        }

        int deg = e1 - e0;
        const float iv = H8INV / (float)(deg > 0 ? deg : 1);   // un-scale + mean
        uint4 o;
        o.x = (unsigned int)to_bf16(a0 * iv) | ((unsigned int)to_bf16(a1 * iv) << 16);
        o.y = (unsigned int)to_bf16(a2 * iv) | ((unsigned int)to_bf16(a3 * iv) << 16);
        o.z = (unsigned int)to_bf16(a4 * iv) | ((unsigned int)to_bf16(a5 * iv) << 16);
        o.w = (unsigned int)to_bf16(a6 * iv) | ((unsigned int)to_bf16(a7 * iv) << 16);
        *(uint4*)(&m_lds[keyLocal * MS + q * 8]) = o;
    }
    __syncthreads();

    // ---- phase B: MFMA, 2 node tiles per wave ----
    const int ct = wid & 3;                    // out-ch tile
    const int ntBase = wid >> 2;               // 0 or 1
    const int koff = (lane >> 4) * 8;          // bf16 element offset in k-block
    const float bv = bias[ct * 16 + (lane & 15)];

#pragma unroll
    for (int tt = 0; tt < 2; ++tt) {
        const int n0 = (ntBase + tt * 2) * 16;     // local node tile base
        const int arowL = n0 + (lane & 15);

        f32x4 acc = {0.f, 0.f, 0.f, 0.f};

#pragma unroll
        for (int r = 0; r < 5; ++r) {
            uint4 a0u, a1u;
            if (r < 4) {
                const unsigned short* ap = &m_lds[(arowL * R_REL + r) * MS];
                a0u = *(const uint4*)(ap + koff);
                a1u = *(const uint4*)(ap + 32 + koff);
            } else {
                const unsigned short* ap = hb_in + (size_t)(nbase + arowL) * D_DIM;
                a0u = *(const uint4*)(ap + koff);
                a1u = *(const uint4*)(ap + 32 + koff);
            }
            const unsigned short* bbase = wfrag + r * 4096 + ct * 512 + lane * 8;
            uint4 b0u = *(const uint4*)bbase;                // kk=0
            uint4 b1u = *(const uint4*)(bbase + 2048);       // kk=1
            acc = __builtin_amdgcn_mfma_f32_16x16x32_bf16(
                __builtin_bit_cast(short8v, a0u), __builtin_bit_cast(short8v, b0u), acc, 0, 0, 0);
            acc = __builtin_amdgcn_mfma_f32_16x16x32_bf16(
                __builtin_bit_cast(short8v, a1u), __builtin_bit_cast(short8v, b1u), acc, 0, 0, 0);
        }

#pragma unroll
        for (int i = 0; i < 4; ++i) {
            float v = acc[i] + bv;
            if (RELU) v = fmaxf(v, 0.f);
            int n = nbase + n0 + (lane >> 4) * 4 + i;
            hb_out[(size_t)n * D_DIM + ct * 16 + (lane & 15)] = to_bf16(v);
            if (RELU)
                hb8_out[(size_t)n * D_DIM + ct * 16 + (lane & 15)] = to_fp8(v * H8SCALE);
        }
    }
}

// ---------------- pooling: run-accumulated (batch is sorted), bf16 input ----------------

__global__ __launch_bounds__(1024) void k_pool(const unsigned short* __restrict__ hb,
                                               const int* __restrict__ batch,
                                               float* __restrict__ partial) {
    __shared__ float bin[G_GRAPHS * D_DIM];   // 16 KB
    int tid = threadIdx.x, lane = tid & 63, wid = tid >> 6;
    for (int i = tid; i < G_GRAPHS * D_DIM; i += 1024) bin[i] = 0.f;
    __syncthreads();
    const int per = (N_NODES + POOL_BLOCKS - 1) / POOL_BLOCKS;
    int n0 = blockIdx.x * per;
    int n1 = n0 + per; if (n1 > N_NODES) n1 = N_NODES;
    int cntw = n1 - n0;
    int sub = (cntw + 15) >> 4;
    int w0 = n0 + wid * sub;
    int w1 = w0 + sub; if (w1 > n1) w1 = n1;

    float acc = 0.f;
    int cur = -1;
    for (int n = w0; n < w1; ++n) {
        int b = __builtin_amdgcn_readfirstlane(batch[n]);
        unsigned int u = hb[(size_t)n * D_DIM + lane];
        float v = __uint_as_float(u << 16);
        if (b != cur) {
            if (cur >= 0) atomicAdd(&bin[cur * D_DIM + lane], acc);
            cur = b;
            acc = v;
        } else {
            acc += v;
        }
    }
    if (cur >= 0) atomicAdd(&bin[cur * D_DIM + lane], acc);
    __syncthreads();
    for (int i = tid; i < G_GRAPHS * D_DIM; i += 1024)
        partial[blockIdx.x * (G_GRAPHS * D_DIM) + i] = bin[i];
}

__global__ void k_pool_reduce(const float* __restrict__ partial,
                              float* __restrict__ pooled) {
    int i = blockIdx.x * blockDim.x + threadIdx.x;   // 4096
    if (i < G_GRAPHS * D_DIM) {
        float s = 0.f;
        for (int b = 0; b < POOL_BLOCKS; ++b) s += partial[b * (G_GRAPHS * D_DIM) + i];
        pooled[i] = s;
    }
}

// ---------------- head ----------------

__global__ void k_head(const float* __restrict__ pooled, const int* __restrict__ start,
                       const float* __restrict__ fc1w, const float* __restrict__ fc1b,
                       const float* __restrict__ fc2w, const float* __restrict__ fc2b,
                       float* __restrict__ out) {
    __shared__ float p[G_GRAPHS][D_DIM];
    __shared__ float hf[G_GRAPHS][D_DIM];
    __shared__ float sc[G_GRAPHS][C_CLS];
    int t = threadIdx.x;

    for (int i = t; i < G_GRAPHS * D_DIM; i += 1024) {
        int g = i >> 6;
        int c = start[g + 1] - start[g];
        p[g][i & 63] = pooled[i] / (float)(c > 0 ? c : 1);
    }
    __syncthreads();

    for (int i = t; i < G_GRAPHS * D_DIM; i += 1024) {
        int g = i >> 6, o = i & 63;
        float a = fc1b[o];
#pragma unroll
        for (int d = 0; d < D_DIM; ++d) a = fmaf(p[g][d], fc1w[d * D_DIM + o], a);
        hf[g][o] = fmaxf(a, 0.f);
    }
    __syncthreads();

    if (t < G_GRAPHS * C_CLS) {
        int g = t / C_CLS, c = t % C_CLS;
        float a = fc2b[c];
#pragma unroll
        for (int d = 0; d < D_DIM; ++d) a = fmaf(hf[g][d], fc2w[d * C_CLS + c], a);
        sc[g][c] = a;
    }
    __syncthreads();

    if (t < G_GRAPHS) {
        float m = -1e30f;
#pragma unroll
        for (int c = 0; c < C_CLS; ++c) m = fmaxf(m, sc[t][c]);
        float s = 0.f;
#pragma unroll
        for (int c = 0; c < C_CLS; ++c) s += expf(sc[t][c] - m);
        float lse = m + logf(s);
#pragma unroll
        for (int c = 0; c < C_CLS; ++c) out[t * C_CLS + c] = sc[t][c] - lse;
    }
}

// ---------------- launch ----------------
// ws budget ~116 MB: off 3.2 + srcSorted 16 + hb0/1 51.2 + hb8_0/1 25.6 +
// coarse 17.6 + wfrag 0.12 + partial 2.1 + small

extern "C" void kernel_launch(void* const* d_in, const int* in_sizes, int n_in,
                              void* d_out, int out_size, void* d_ws, size_t ws_size,
                              hipStream_t stream) {
    const int*   x_op    = (const int*)d_in[0];
    const int*   x_cat   = (const int*)d_in[1];
    const int*   eidx    = (const int*)d_in[2];
    const int*   src     = eidx;
    const int*   tgt     = eidx + N_EDGES;
    const int*   etype   = (const int*)d_in[3];
    const int*   batch   = (const int*)d_in[4];
    const float* op_emb  = (const float*)d_in[5];
    const float* cat_emb = (const float*)d_in[6];
    const float* w1 = (const float*)d_in[7];
    const float* r1 = (const float*)d_in[8];
    const float* b1 = (const float*)d_in[9];
    const float* w2 = (const float*)d_in[10];
    const float* r2 = (const float*)d_in[11];
    const float* b2 = (const float*)d_in[12];
    const float* w3 = (const float*)d_in[13];
    const float* r3 = (const float*)d_in[14];
    const float* b3 = (const float*)d_in[15];
    const float* fc1w = (const float*)d_in[16];
    const float* fc1b = (const float*)d_in[17];
    const float* fc2w = (const float*)d_in[18];
    const float* fc2b = (const float*)d_in[19];
    float* out = (float*)d_out;

    char* ws = (char*)d_ws;
    size_t o = 0;
    auto alloc = [&](size_t bytes) -> void* {
        o = (o + 255) & ~(size_t)255;
        void* p = ws + o;
        o += bytes;
        return p;
    };

    int*   off        = (int*)alloc((size_t)(NR + 1) * 4);
    int*   srcSorted  = (int*)alloc((size_t)N_EDGES * 4);
    unsigned short* hb0   = (unsigned short*)alloc((size_t)N_NODES * D_DIM * 2);
    unsigned short* hb1   = (unsigned short*)alloc((size_t)N_NODES * D_DIM * 2);
    unsigned char*  hb8_0 = (unsigned char*)alloc((size_t)N_NODES * D_DIM);
    unsigned char*  hb8_1 = (unsigned char*)alloc((size_t)N_NODES * D_DIM);
    unsigned int*   coarse = (unsigned int*)alloc((size_t)NCB * CCAP * 4);   // 17.6 MB
    unsigned short* wfrag = (unsigned short*)alloc((size_t)15 * 4096 * 2);
    float* partial    = (float*)alloc((size_t)POOL_BLOCKS * G_GRAPHS * D_DIM * 4);
    float* pooled     = (float*)alloc((size_t)G_GRAPHS * D_DIM * 4);
    int*   startg     = (int*)alloc((size_t)(G_GRAPHS + 1) * 4);
    int*   gcur       = (int*)alloc((size_t)NCB * 4);

    hipMemsetAsync(gcur, 0, (size_t)NCB * 4, stream);

    // CSR build: LDS-staged 2-pass radix (all writes contiguous runs)
    k_coarse<<<(N_EDGES + EPB - 1) / EPB, 512, 0, stream>>>(src, tgt, etype, gcur, coarse);
    k_fine<<<NCB, 1024, 0, stream>>>(gcur, coarse, off, srcSorted);

    // embed + bounds + weight prep (fused)
    WPtrs wp;
    wp.p[0] = w1;          wp.p[1] = w1 + 4096;  wp.p[2] = w1 + 8192;  wp.p[3] = w1 + 12288;
    wp.p[4] = r1;
    wp.p[5] = w2;          wp.p[6] = w2 + 4096;  wp.p[7] = w2 + 8192;  wp.p[8] = w2 + 12288;
    wp.p[9] = r2;
    wp.p[10] = w3;         wp.p[11] = w3 + 4096; wp.p[12] = w3 + 8192; wp.p[13] = w3 + 12288;
    wp.p[14] = r3;
    k_misc<<<EMBED_BLOCKS + BOUNDS_BLOCKS + 15, 256, 0, stream>>>(
        x_op, x_cat, (const float4*)op_emb, (const float4*)cat_emb,
        (ushort4*)hb0, (uchar4*)hb8_0, batch, startg, wp, wfrag);

    const int layerBlocks = N_NODES / 64;        // 3125

    k_layer<1><<<layerBlocks, 512, 0, stream>>>(
        hb0, hb8_0, hb1, hb8_1, off, srcSorted, wfrag, b1);
    k_layer<1><<<layerBlocks, 512, 0, stream>>>(
        hb1, hb8_1, hb0, hb8_0, off, srcSorted, wfrag + 5 * 4096, b2);
    k_layer<0><<<layerBlocks, 512, 0, stream>>>(
        hb0, hb8_0, hb1, hb8_1, off, srcSorted, wfrag + 10 * 4096, b3);

    k_pool<<<POOL_BLOCKS, 1024, 0, stream>>>(hb1, batch, partial);
    k_pool_reduce<<<(G_GRAPHS * D_DIM + 255) / 256, 256, 0, stream>>>(partial, pooled);
    k_head<<<1, 1024, 0, stream>>>(pooled, startg, fc1w, fc1b, fc2w, fc2b, out);
}

// Round 14
// 407.208 us; speedup vs baseline: 1.0518x; 1.0518x over previous
//
#include <hip/hip_runtime.h>
#include <hip/hip_bf16.h>

#define N_NODES 200000
#define N_EDGES 4000000
#define R_REL   4
#define D_DIM   64
#define G_GRAPHS 64
#define C_CLS   10
#define NR      (N_NODES * R_REL)      // 800000
#define POOL_BLOCKS 128

// 2-pass radix CSR build
#define NCB   391                       // ceil(NR / 2048) coarse buckets (key>>11)
#define LCAP  64                        // LDS bin cap (lambda=20.9, +9.3 sigma)
#define CCAP  11264                     // coarse bucket cap (lambda=10230, +10 sigma)
#define EPB   8192                      // edges per k_coarse block (512 thr x 16)

#define EMBED_BLOCKS 12500              // N*16/256
#define BOUNDS_BLOCKS 782               // ceil(N/256)

#define MS    72                        // m_lds row stride in shorts (144 B)

typedef __attribute__((ext_vector_type(8))) short short8v;   // 8 bf16 (4 VGPR)
typedef __attribute__((ext_vector_type(4))) float f32x4;

__device__ __forceinline__ unsigned short to_bf16(float x) {
    __hip_bfloat16 b = __float2bfloat16(x);
    return *(unsigned short*)&b;
}

#define ACC8(u) \
    a0 += __uint_as_float((u).x << 16); \
    a1 += __uint_as_float((u).x & 0xFFFF0000u); \
    a2 += __uint_as_float((u).y << 16); \
    a3 += __uint_as_float((u).y & 0xFFFF0000u); \
    a4 += __uint_as_float((u).z << 16); \
    a5 += __uint_as_float((u).z & 0xFFFF0000u); \
    a6 += __uint_as_float((u).w << 16); \
    a7 += __uint_as_float((u).w & 0xFFFF0000u);

// ---------------- CSR build pass 1: LDS-staged coarse binning ----------------
// entry = (key & 2047) << 18 | src   (11 + 18 bits)

__global__ __launch_bounds__(512) void k_coarse(
    const int* __restrict__ src, const int* __restrict__ tgt,
    const int* __restrict__ et,
    int* __restrict__ gcur, unsigned int* __restrict__ coarse) {
    __shared__ unsigned int bins[NCB * LCAP];   // 100 KB
    __shared__ int lcnt[NCB], lpos[NCB];

    const int tid = threadIdx.x;
    for (int i = tid; i < NCB; i += 512) lcnt[i] = 0;
    __syncthreads();

#pragma unroll
    for (int h = 0; h < 4; ++h) {
        int e4 = blockIdx.x * EPB + (h * 512 + tid) * 4;
        if (e4 < N_EDGES) {
            int4 s = *(const int4*)&src[e4];
            int4 t = *(const int4*)&tgt[e4];
            int4 r = *(const int4*)&et[e4];
#define PUT(ss, tt, rr) { \
                int key = (tt) * R_REL + (rr); \
                int b = key >> 11; \
                int p = atomicAdd(&lcnt[b], 1); \
                if (p < LCAP) bins[b * LCAP + p] = \
                    ((unsigned int)(key & 2047) << 18) | (unsigned int)(ss); \
            }
            PUT(s.x, t.x, r.x); PUT(s.y, t.y, r.y);
            PUT(s.z, t.z, r.z); PUT(s.w, t.w, r.w);
#undef PUT
        }
    }
    __syncthreads();

    for (int i = tid; i < NCB; i += 512) {
        int c = lcnt[i]; if (c > LCAP) c = LCAP;
        lcnt[i] = c;
        lpos[i] = atomicAdd(&gcur[i], c);
    }
    __syncthreads();

    for (int j = tid; j < NCB * LCAP; j += 512) {
        int b = j >> 6, l = j & 63;
        if (l < lcnt[b]) {
            int gp = lpos[b] + l;
            if (gp < CCAP) coarse[(size_t)b * CCAP + gp] = bins[j];
        }
    }
}

// ---------------- CSR build pass 2: per-bucket fine counting sort ----------------

__global__ __launch_bounds__(1024) void k_fine(
    const int* __restrict__ gcur, const unsigned int* __restrict__ coarse,
    int* __restrict__ off, int* __restrict__ srcSorted) {
    __shared__ unsigned int ent[CCAP];   // 45 KB
    __shared__ int hist[2048];           // 8 KB
    __shared__ int pre[512];             // 2 KB

    const int cb = blockIdx.x, tid = threadIdx.x;

    int v = 0;
    if (tid < 512) {
        v = (tid < NCB) ? gcur[tid] : 0;
        if (v > CCAP) v = CCAP;
        pre[tid] = v;
    }
    __syncthreads();
    for (int d = 1; d < 512; d <<= 1) {
        int t = 0;
        if (tid < 512 && tid >= d) t = pre[tid - d];
        __syncthreads();
        if (tid < 512) pre[tid] += t;
        __syncthreads();
    }
    const int gb = (cb > 0) ? pre[cb - 1] : 0;

    int cnt = gcur[cb]; if (cnt > CCAP) cnt = CCAP;
    const int key0 = cb << 11;
    const unsigned int* cp = coarse + (size_t)cb * CCAP;

    for (int i = tid; i < cnt; i += 1024) ent[i] = cp[i];
    hist[tid] = 0; hist[tid + 1024] = 0;
    __syncthreads();

    for (int i = tid; i < cnt; i += 1024) atomicAdd(&hist[ent[i] >> 18], 1);
    __syncthreads();

    int x0 = hist[tid], x1 = hist[tid + 1024];
    for (int d = 1; d < 2048; d <<= 1) {
        int v0 = (tid >= d) ? hist[tid - d] : 0;
        int v1 = hist[tid + 1024 - d];
        __syncthreads();
        hist[tid] += v0;
        hist[tid + 1024] += v1;
        __syncthreads();
    }
    int excl0 = hist[tid] - x0;
    int excl1 = hist[tid + 1024] - x1;
    __syncthreads();
    hist[tid] = excl0;                   // becomes scatter cursor
    hist[tid + 1024] = excl1;

    int key = key0 + tid;
    if (key < NR) off[key] = gb + excl0;
    key = key0 + tid + 1024;
    if (key < NR) off[key] = gb + excl1;
    if (cb == NCB - 1 && tid == 0) off[NR] = N_EDGES;
    __syncthreads();

    for (int i = tid; i < cnt; i += 1024) {
        unsigned int e = ent[i];
        int pos = atomicAdd(&hist[e >> 18], 1);
        srcSorted[gb + pos] = (int)(e & 0x3FFFFu);
    }
}

// ---------------- fused misc: embed + bounds + weight prep ----------------

struct WPtrs { const float* p[15]; };

__global__ void k_misc(const int* __restrict__ xop, const int* __restrict__ xcat,
                       const float4* __restrict__ opemb, const float4* __restrict__ catemb,
                       ushort4* __restrict__ hb,
                       const int* __restrict__ batch, int* __restrict__ start,
                       WPtrs wp, unsigned short* __restrict__ wfrag) {
    int bid = blockIdx.x;
    if (bid < EMBED_BLOCKS) {
        int i = bid * 256 + threadIdx.x;
        if (i < N_NODES * 16) {
            int n = i >> 4, q = i & 15;
            float4 a = opemb[xop[n] * 16 + q];
            float4 b = catemb[xcat[n] * 16 + q];
            ushort4 ub;
            ub.x = to_bf16(a.x + b.x); ub.y = to_bf16(a.y + b.y);
            ub.z = to_bf16(a.z + b.z); ub.w = to_bf16(a.w + b.w);
            hb[i] = ub;
        }
    } else if (bid < EMBED_BLOCKS + BOUNDS_BLOCKS) {
        int i = (bid - EMBED_BLOCKS) * 256 + threadIdx.x;
        if (i >= N_NODES) return;
        int b = batch[i];
        if (i == 0) {
            for (int g = 0; g <= b; ++g) start[g] = 0;
        } else {
            int p = batch[i - 1];
            for (int g = p + 1; g <= b; ++g) start[g] = i;
        }
        if (i == N_NODES - 1) {
            for (int g = b + 1; g <= G_GRAPHS; ++g) start[g] = N_NODES;
        }
    } else {
        int m = bid - EMBED_BLOCKS - BOUNDS_BLOCKS;    // 0..14
        const float* W = wp.p[m];
        unsigned short* outp = wfrag + m * 4096;
        for (int f = threadIdx.x; f < 4096; f += 256) {
            int j = f & 7, lane = (f >> 3) & 63, c0t = (f >> 9) & 3, kk = f >> 11;
            int k  = kk * 32 + (lane >> 4) * 8 + j;
            int ch = c0t * 16 + (lane & 15);
            outp[f] = to_bf16(W[k * 64 + ch]);
        }
    }
}

// ---------------- fused RGCN layer: bf16 gather (8-deep MLP) + MFMA ----------------
// Block = 512 threads (8 waves), 64 nodes = 256 keys; LDS = m_lds only (36.9 KB).
// Phase A: wave w aggregates keys [w*32, w*32+32) in four 8-key register passes.
//   Segment processed in rounds of 8 clamp-masked loads (index clamped to e1-1:
//   duplicate loads MSHR-merge, no extra line traffic) -> 8 rows in flight/lane.
// Phase B: MFMA 16x16x32; wave (ct=wid&3) does node tiles (wid>>2) and (wid>>2)+2.

template <int RELU>
__global__ __launch_bounds__(512) void k_layer(
    const unsigned short* __restrict__ hb_in,   // [N][64] bf16
    unsigned short* __restrict__ hb_out,        // [N][64] bf16
    const int* __restrict__ off, const int* __restrict__ srcSorted,
    const unsigned short* __restrict__ wfrag,   // this layer: [5][2][4][64][8] bf16
    const float* __restrict__ bias)             // [64]
{
    __shared__ unsigned short m_lds[256 * MS];  // 36864 B

    const int tid  = threadIdx.x;
    const int lane = tid & 63, wid = tid >> 6;  // 8 waves
    const int g = lane >> 3, q = lane & 7;
    const int nbase = blockIdx.x * 64;

    // ---- phase A: aggregate 32 keys per wave into m_lds ----
    const unsigned short* base = hb_in + q * 8;
#pragma unroll
    for (int p = 0; p < 4; ++p) {
        const int keyLocal = wid * 32 + p * 8 + g;
        const int key = nbase * R_REL + keyLocal;
        const int e0 = off[key];
        const int e1 = off[key + 1];
        const int last = e1 - 1;

        float a0 = 0.f, a1 = 0.f, a2 = 0.f, a3 = 0.f,
              a4 = 0.f, a5 = 0.f, a6 = 0.f, a7 = 0.f;

        for (int e = e0; e < e1; e += 8) {
            int s[8];
#pragma unroll
            for (int k = 0; k < 8; ++k) {
                int ee = e + k;
                ee = (ee > last) ? last : ee;
                s[k] = srcSorted[ee];
            }
            uint4 u[8];
#pragma unroll
            for (int k = 0; k < 8; ++k)
                u[k] = *(const uint4*)(base + (size_t)s[k] * D_DIM);
            const int rem = e1 - e;
#pragma unroll
            for (int k = 0; k < 8; ++k) {
                if (k < rem) { ACC8(u[k]); }
            }
        }

        int deg = e1 - e0;
        const float iv = 1.0f / (float)(deg > 0 ? deg : 1);
        uint4 o;
        o.x = (unsigned int)to_bf16(a0 * iv) | ((unsigned int)to_bf16(a1 * iv) << 16);
        o.y = (unsigned int)to_bf16(a2 * iv) | ((unsigned int)to_bf16(a3 * iv) << 16);
        o.z = (unsigned int)to_bf16(a4 * iv) | ((unsigned int)to_bf16(a5 * iv) << 16);
        o.w = (unsigned int)to_bf16(a6 * iv) | ((unsigned int)to_bf16(a7 * iv) << 16);
        *(uint4*)(&m_lds[keyLocal * MS + q * 8]) = o;
    }
    __syncthreads();

    // ---- phase B: MFMA, 2 node tiles per wave ----
    const int ct = wid & 3;                    // out-ch tile
    const int ntBase = wid >> 2;               // 0 or 1
    const int koff = (lane >> 4) * 8;          // bf16 element offset in k-block
    const float bv = bias[ct * 16 + (lane & 15)];

#pragma unroll
    for (int tt = 0; tt < 2; ++tt) {
        const int n0 = (ntBase + tt * 2) * 16;     // local node tile base
        const int arowL = n0 + (lane & 15);

        f32x4 acc = {0.f, 0.f, 0.f, 0.f};

#pragma unroll
        for (int r = 0; r < 5; ++r) {
            uint4 a0u, a1u;
            if (r < 4) {
                const unsigned short* ap = &m_lds[(arowL * R_REL + r) * MS];
                a0u = *(const uint4*)(ap + koff);
                a1u = *(const uint4*)(ap + 32 + koff);
            } else {
                const unsigned short* ap = hb_in + (size_t)(nbase + arowL) * D_DIM;
                a0u = *(const uint4*)(ap + koff);
                a1u = *(const uint4*)(ap + 32 + koff);
            }
            const unsigned short* bbase = wfrag + r * 4096 + ct * 512 + lane * 8;
            uint4 b0u = *(const uint4*)bbase;                // kk=0
            uint4 b1u = *(const uint4*)(bbase + 2048);       // kk=1
            acc = __builtin_amdgcn_mfma_f32_16x16x32_bf16(
                __builtin_bit_cast(short8v, a0u), __builtin_bit_cast(short8v, b0u), acc, 0, 0, 0);
            acc = __builtin_amdgcn_mfma_f32_16x16x32_bf16(
                __builtin_bit_cast(short8v, a1u), __builtin_bit_cast(short8v, b1u), acc, 0, 0, 0);
        }

#pragma unroll
        for (int i = 0; i < 4; ++i) {
            float v = acc[i] + bv;
            if (RELU) v = fmaxf(v, 0.f);
            int n = nbase + n0 + (lane >> 4) * 4 + i;
            hb_out[(size_t)n * D_DIM + ct * 16 + (lane & 15)] = to_bf16(v);
        }
    }
}

// ---------------- pooling: run-accumulated (batch is sorted), bf16 input ----------------

__global__ __launch_bounds__(1024) void k_pool(const unsigned short* __restrict__ hb,
                                               const int* __restrict__ batch,
                                               float* __restrict__ partial) {
    __shared__ float bin[G_GRAPHS * D_DIM];   // 16 KB
    int tid = threadIdx.x, lane = tid & 63, wid = tid >> 6;
    for (int i = tid; i < G_GRAPHS * D_DIM; i += 1024) bin[i] = 0.f;
    __syncthreads();
    const int per = (N_NODES + POOL_BLOCKS - 1) / POOL_BLOCKS;
    int n0 = blockIdx.x * per;
    int n1 = n0 + per; if (n1 > N_NODES) n1 = N_NODES;
    int cntw = n1 - n0;
    int sub = (cntw + 15) >> 4;
    int w0 = n0 + wid * sub;
    int w1 = w0 + sub; if (w1 > n1) w1 = n1;

    float acc = 0.f;
    int cur = -1;
    for (int n = w0; n < w1; ++n) {
        int b = __builtin_amdgcn_readfirstlane(batch[n]);
        unsigned int u = hb[(size_t)n * D_DIM + lane];
        float v = __uint_as_float(u << 16);
        if (b != cur) {
            if (cur >= 0) atomicAdd(&bin[cur * D_DIM + lane], acc);
            cur = b;
            acc = v;
        } else {
            acc += v;
        }
    }
    if (cur >= 0) atomicAdd(&bin[cur * D_DIM + lane], acc);
    __syncthreads();
    for (int i = tid; i < G_GRAPHS * D_DIM; i += 1024)
        partial[blockIdx.x * (G_GRAPHS * D_DIM) + i] = bin[i];
}

__global__ void k_pool_reduce(const float* __restrict__ partial,
                              float* __restrict__ pooled) {
    int i = blockIdx.x * blockDim.x + threadIdx.x;   // 4096
    if (i < G_GRAPHS * D_DIM) {
        float s = 0.f;
        for (int b = 0; b < POOL_BLOCKS; ++b) s += partial[b * (G_GRAPHS * D_DIM) + i];
        pooled[i] = s;
    }
}

// ---------------- head ----------------

__global__ void k_head(const float* __restrict__ pooled, const int* __restrict__ start,
                       const float* __restrict__ fc1w, const float* __restrict__ fc1b,
                       const float* __restrict__ fc2w, const float* __restrict__ fc2b,
                       float* __restrict__ out) {
    __shared__ float p[G_GRAPHS][D_DIM];
    __shared__ float hf[G_GRAPHS][D_DIM];
    __shared__ float sc[G_GRAPHS][C_CLS];
    int t = threadIdx.x;

    for (int i = t; i < G_GRAPHS * D_DIM; i += 1024) {
        int g = i >> 6;
        int c = start[g + 1] - start[g];
        p[g][i & 63] = pooled[i] / (float)(c > 0 ? c : 1);
    }
    __syncthreads();

    for (int i = t; i < G_GRAPHS * D_DIM; i += 1024) {
        int g = i >> 6, o = i & 63;
        float a = fc1b[o];
#pragma unroll
        for (int d = 0; d < D_DIM; ++d) a = fmaf(p[g][d], fc1w[d * D_DIM + o], a);
        hf[g][o] = fmaxf(a, 0.f);
    }
    __syncthreads();

    if (t < G_GRAPHS * C_CLS) {
        int g = t / C_CLS, c = t % C_CLS;
        float a = fc2b[c];
#pragma unroll
        for (int d = 0; d < D_DIM; ++d) a = fmaf(hf[g][d], fc2w[d * C_CLS + c], a);
        sc[g][c] = a;
    }
    __syncthreads();

    if (t < G_GRAPHS) {
        float m = -1e30f;
#pragma unroll
        for (int c = 0; c < C_CLS; ++c) m = fmaxf(m, sc[t][c]);
        float s = 0.f;
#pragma unroll
        for (int c = 0; c < C_CLS; ++c) s += expf(sc[t][c] - m);
        float lse = m + logf(s);
#pragma unroll
        for (int c = 0; c < C_CLS; ++c) out[t * C_CLS + c] = sc[t][c] - lse;
    }
}

// ---------------- launch ----------------
// ws budget ~90 MB: off 3.2 + srcSorted 16 + hb0 25.6 + hb1 25.6 + coarse 17.6 +
// wfrag 0.12 + partial 2.1 + small

extern "C" void kernel_launch(void* const* d_in, const int* in_sizes, int n_in,
                              void* d_out, int out_size, void* d_ws, size_t ws_size,
                              hipStream_t stream) {
    const int*   x_op    = (const int*)d_in[0];
    const int*   x_cat   = (const int*)d_in[1];
    const int*   eidx    = (const int*)d_in[2];
    const int*   src     = eidx;
    const int*   tgt     = eidx + N_EDGES;
    const int*   etype   = (const int*)d_in[3];
    const int*   batch   = (const int*)d_in[4];
    const float* op_emb  = (const float*)d_in[5];
    const float* cat_emb = (const float*)d_in[6];
    const float* w1 = (const float*)d_in[7];
    const float* r1 = (const float*)d_in[8];
    const float* b1 = (const float*)d_in[9];
    const float* w2 = (const float*)d_in[10];
    const float* r2 = (const float*)d_in[11];
    const float* b2 = (const float*)d_in[12];
    const float* w3 = (const float*)d_in[13];
    const float* r3 = (const float*)d_in[14];
    const float* b3 = (const float*)d_in[15];
    const float* fc1w = (const float*)d_in[16];
    const float* fc1b = (const float*)d_in[17];
    const float* fc2w = (const float*)d_in[18];
    const float* fc2b = (const float*)d_in[19];
    float* out = (float*)d_out;

    char* ws = (char*)d_ws;
    size_t o = 0;
    auto alloc = [&](size_t bytes) -> void* {
        o = (o + 255) & ~(size_t)255;
        void* p = ws + o;
        o += bytes;
        return p;
    };

    int*   off        = (int*)alloc((size_t)(NR + 1) * 4);
    int*   srcSorted  = (int*)alloc((size_t)N_EDGES * 4);
    unsigned short* hb0   = (unsigned short*)alloc((size_t)N_NODES * D_DIM * 2);
    unsigned short* hb1   = (unsigned short*)alloc((size_t)N_NODES * D_DIM * 2);
    unsigned int*   coarse = (unsigned int*)alloc((size_t)NCB * CCAP * 4);   // 17.6 MB
    unsigned short* wfrag = (unsigned short*)alloc((size_t)15 * 4096 * 2);
    float* partial    = (float*)alloc((size_t)POOL_BLOCKS * G_GRAPHS * D_DIM * 4);
    float* pooled     = (float*)alloc((size_t)G_GRAPHS * D_DIM * 4);
    int*   startg     = (int*)alloc((size_t)(G_GRAPHS + 1) * 4);
    int*   gcur       = (int*)alloc((size_t)NCB * 4);

    hipMemsetAsync(gcur, 0, (size_t)NCB * 4, stream);

    // CSR build: LDS-staged 2-pass radix (all writes contiguous runs)
    k_coarse<<<(N_EDGES + EPB - 1) / EPB, 512, 0, stream>>>(src, tgt, etype, gcur, coarse);
    k_fine<<<NCB, 1024, 0, stream>>>(gcur, coarse, off, srcSorted);

    // embed + bounds + weight prep (fused)
    WPtrs wp;
    wp.p[0] = w1;          wp.p[1] = w1 + 4096;  wp.p[2] = w1 + 8192;  wp.p[3] = w1 + 12288;
    wp.p[4] = r1;
    wp.p[5] = w2;          wp.p[6] = w2 + 4096;  wp.p[7] = w2 + 8192;  wp.p[8] = w2 + 12288;
    wp.p[9] = r2;
    wp.p[10] = w3;         wp.p[11] = w3 + 4096; wp.p[12] = w3 + 8192; wp.p[13] = w3 + 12288;
    wp.p[14] = r3;
    k_misc<<<EMBED_BLOCKS + BOUNDS_BLOCKS + 15, 256, 0, stream>>>(
        x_op, x_cat, (const float4*)op_emb, (const float4*)cat_emb, (ushort4*)hb0,
        batch, startg, wp, wfrag);

    const int layerBlocks = N_NODES / 64;        // 3125

    k_layer<1><<<layerBlocks, 512, 0, stream>>>(hb0, hb1, off, srcSorted, wfrag, b1);
    k_layer<1><<<layerBlocks, 512, 0, stream>>>(hb1, hb0, off, srcSorted, wfrag + 5 * 4096, b2);
    k_layer<0><<<layerBlocks, 512, 0, stream>>>(hb0, hb1, off, srcSorted, wfrag + 10 * 4096, b3);

    k_pool<<<POOL_BLOCKS, 1024, 0, stream>>>(hb1, batch, partial);
    k_pool_reduce<<<(G_GRAPHS * D_DIM + 255) / 256, 256, 0, stream>>>(partial, pooled);
    k_head<<<1, 1024, 0, stream>>>(pooled, startg, fc1w, fc1b, fc2w, fc2b, out);
}